// Round 8
// baseline (240.612 us; speedup 1.0000x reference)
//
#include <hip/hip_runtime.h>
#include <math.h>

typedef __attribute__((ext_vector_type(4))) float  floatx4;
typedef __attribute__((ext_vector_type(8))) short  short8;
typedef __attribute__((ext_vector_type(4))) short  short4v;
typedef __attribute__((ext_vector_type(8))) __bf16 bf16x8;

#define E_DIM 768
#define T_DIM 2048
#define N_B   2
#define N_H   12
#define H_D   64
#define M_TOT 4096  /* N_B * T_DIM */

// 0.125 * log2(e): folded into Q so exp2() applies directly to QK^T output
#define Q_SCALE 0.1803368801111204f

#if __has_builtin(__builtin_amdgcn_exp2f)
#define EXP2F(x) __builtin_amdgcn_exp2f(x)
#else
#define EXP2F(x) exp2f(x)
#endif
#if __has_builtin(__builtin_amdgcn_rcpf)
#define RCPF(x) __builtin_amdgcn_rcpf(x)
#else
#define RCPF(x) (1.0f / (x))
#endif

__device__ __forceinline__ unsigned short f32_to_bf16(float f) {
  unsigned int u = __float_as_uint(f);
  u += 0x7fffu + ((u >> 16) & 1u);
  return (unsigned short)(u >> 16);
}

// truncating f32->bf16 (bias cancels in o/l since num+denom share P)
__device__ __forceinline__ unsigned short f32_to_bf16_trunc(float f) {
  return (unsigned short)(__float_as_uint(f) >> 16);
}

__device__ __forceinline__ void gload_lds16(const unsigned short* g, unsigned short* l) {
  __builtin_amdgcn_global_load_lds(
      (const __attribute__((address_space(1))) unsigned int*)(const void*)g,
      (__attribute__((address_space(3))) unsigned int*)(void*)l, 16, 0, 0);
}

// ---- prep: input bf16 convert (blocks 0..9215) + weight transpose (blocks 9216..11519) ----
__global__ __launch_bounds__(256) void prep(const float* __restrict__ q,
                                            const float* __restrict__ k,
                                            const float* __restrict__ v,
                                            const float* __restrict__ W0,
                                            const float* __restrict__ W1,
                                            const float* __restrict__ W2,
                                            const float* __restrict__ W3,
                                            unsigned short* __restrict__ Xb,
                                            unsigned short* __restrict__ Wt) {
  __shared__ float tile[32][33];
  const int bx = blockIdx.x;
  if (bx < 9216) {
    const int z = bx / 3072, inner = bx % 3072;
    const float* src = (z == 0) ? q : (z == 1) ? k : v;
    size_t idx = ((size_t)inner * 256 + threadIdx.x) * 4;
    float4 val = *reinterpret_cast<const float4*>(&src[idx]);
    short4v o;
    o[0] = (short)f32_to_bf16(val.x);
    o[1] = (short)f32_to_bf16(val.y);
    o[2] = (short)f32_to_bf16(val.z);
    o[3] = (short)f32_to_bf16(val.w);
    *reinterpret_cast<short4v*>(&Xb[(size_t)z * M_TOT * E_DIM + idx]) = o;
  } else {
    const int t = bx - 9216;
    const int z = t / 576, rem = t % 576;
    const float* W = (z == 0) ? W0 : (z == 1) ? W1 : (z == 2) ? W2 : W3;
    unsigned short* dst = Wt + (size_t)z * E_DIM * E_DIM;
    int k0 = (rem / 24) * 32, n0 = (rem % 24) * 32;
    int tx = threadIdx.x & 31, ty = threadIdx.x >> 5;
    for (int i = 0; i < 4; i++)
      tile[ty + i * 8][tx] = W[(size_t)(k0 + ty + i * 8) * E_DIM + n0 + tx];
    __syncthreads();
    for (int i = 0; i < 4; i++)
      dst[(size_t)(n0 + ty + i * 8) * E_DIM + k0 + tx] = f32_to_bf16(tile[tx][ty + i * 8]);
  }
}

// ---- QKV projection: BK=64 (half the barriers), XOR-swizzled chunk staging.
// z=2 (V) writes transposed VT[b][h][d][t] directly.
__global__ __launch_bounds__(256) void gemm_qkv(const unsigned short* __restrict__ Xb,
                                                const unsigned short* __restrict__ WtAll,
                                                const float* __restrict__ bq,
                                                const float* __restrict__ bk,
                                                const float* __restrict__ bv,
                                                unsigned short* __restrict__ outQKV,
                                                unsigned short* __restrict__ VTout) {
  __shared__ unsigned short As[128 * 64];  // [row][col], chunk (row,dc) holds global dc^(row&7)
  __shared__ unsigned short Bs[128 * 64];

  const int z = blockIdx.z;
  const unsigned short* A = Xb + (size_t)z * M_TOT * E_DIM;
  const float* bias = (z == 0) ? bq : (z == 1) ? bk : bv;
  const unsigned short* W = WtAll + (size_t)z * E_DIM * E_DIM;
  unsigned short* out = outQKV + (size_t)z * M_TOT * E_DIM;
  const float scale = (z == 0) ? Q_SCALE : 1.0f;

  const int tid = threadIdx.x;
  const int lane = tid & 63, wv = tid >> 6;
  const int m15 = lane & 15, quad = lane >> 4;
  const int wm = (wv & 1) * 64, wn = (wv >> 1) * 64;
  const int m0 = blockIdx.x * 128, n0 = blockIdx.y * 128;

  floatx4 acc[4][4] = {};
  const int sw = m15 & 7;  // read-side chunk swizzle key

  for (int k0 = 0; k0 < E_DIM; k0 += 64) {
#pragma unroll
    for (int i = 0; i < 4; i++) {
      int c = tid + i * 256;           // chunk id 0..1023
      int row = c >> 3, dc = c & 7;
      int dcs = dc ^ (row & 7);
      gload_lds16(&A[(size_t)(m0 + row) * E_DIM + k0 + dcs * 8], &As[c * 8]);
      gload_lds16(&W[(size_t)(n0 + row) * E_DIM + k0 + dcs * 8], &Bs[c * 8]);
    }
    __syncthreads();
#pragma unroll
    for (int kk = 0; kk < 2; kk++) {
      bf16x8 af[4], bfr[4];
      for (int i = 0; i < 4; i++)
        af[i] = *reinterpret_cast<const bf16x8*>(
            &As[(wm + i * 16 + m15) * 64 + (((kk * 4 + quad) ^ sw) * 8)]);
      for (int j = 0; j < 4; j++)
        bfr[j] = *reinterpret_cast<const bf16x8*>(
            &Bs[(wn + j * 16 + m15) * 64 + (((kk * 4 + quad) ^ sw) * 8)]);
      for (int i = 0; i < 4; i++)
        for (int j = 0; j < 4; j++)
          acc[i][j] = __builtin_amdgcn_mfma_f32_16x16x32_bf16(af[i], bfr[j], acc[i][j], 0, 0, 0);
    }
    __syncthreads();
  }

  if (z == 2) {
    for (int i = 0; i < 4; i++)
      for (int j = 0; j < 4; j++) {
        int gn = n0 + wn + j * 16 + m15;
        int hh = gn >> 6, d = gn & 63;
        float bso = bias[gn];
        int gm0 = m0 + wm + i * 16 + quad * 4;
        int bb2 = gm0 >> 11, t0 = gm0 & 2047;
        unsigned int d0 = ((unsigned int)f32_to_bf16(acc[i][j][1] + bso) << 16) |
                          f32_to_bf16(acc[i][j][0] + bso);
        unsigned int d1 = ((unsigned int)f32_to_bf16(acc[i][j][3] + bso) << 16) |
                          f32_to_bf16(acc[i][j][2] + bso);
        uint2 dd; dd.x = d0; dd.y = d1;
        *reinterpret_cast<uint2*>(
            &VTout[(((size_t)bb2 * N_H + hh) * H_D + d) * T_DIM + t0]) = dd;
      }
  } else {
    for (int i = 0; i < 4; i++)
      for (int j = 0; j < 4; j++) {
        int gn = n0 + wn + j * 16 + m15;
        int h = gn >> 6, d = gn & 63;
        float bso = bias[gn];
        for (int r = 0; r < 4; r++) {
          int gm = m0 + wm + i * 16 + quad * 4 + r;
          int bb = gm >> 11, tt = gm & 2047;
          float vv = (acc[i][j][r] + bso) * scale;
          out[(((size_t)bb * N_H + h) * T_DIM + tt) * H_D + d] = f32_to_bf16(vv);
        }
      }
  }
}

// ---- flash attention: BARRIER-FREE main loop. 256 thr, qs x ks wave split.
// K and V fragments streamed from global (L2) into registers, consume-then-refill
// with one full round of slack. LDS only holds per-wave P strips (ping-pong for
// lagged PV: round r does PV(t_{r-1}) then QK(t_r)). No-max softmax; l via
// ones-MFMA; cross-ks reduction through LDS at the end (O, l are pure sums).
__global__ __launch_bounds__(256, 3) void attn(const unsigned short* __restrict__ QKV,
                                               const unsigned short* __restrict__ VT,
                                               unsigned short* __restrict__ ctx) {
  __shared__ unsigned short strips[4][2][32 * 72];  // [wave][ping][q][key] 36.9 KB

  const int qb = blockIdx.x, h = blockIdx.y, bb = blockIdx.z;
  const size_t headoff = (((size_t)bb * N_H + h) * T_DIM) * H_D;
  const unsigned short* Qg = QKV + headoff;
  const unsigned short* Kg = QKV + (size_t)M_TOT * E_DIM + headoff;
  const unsigned short* VTg = VT + (((size_t)bb * N_H + h) * H_D) * T_DIM;

  const int tid = threadIdx.x, lane = tid & 63, wv = tid >> 6;
  const int m15 = lane & 15, quad = lane >> 4;
  const int qs = wv & 1, ks = wv >> 1;
  const int q0 = qb * 64 + qs * 32;

  // wave handles tiles t_r = 2r + ks, r = 0..15
  const unsigned short* kbase = Kg + (size_t)(m15 * 64 + quad * 8);
  const unsigned short* vbase = VTg + (size_t)(m15 * 2048 + quad * 8);
#define KFRAG(kt, mt, kk) \
  (*reinterpret_cast<const short8*>(kbase + (size_t)(kt) * 4096 + (mt) * 1024 + (kk) * 32))
#define VFRAG(kt, nt, kk2) \
  (*reinterpret_cast<const short8*>(vbase + (size_t)(nt) * 32768 + (kt) * 64 + (kk2) * 32))

  // Q fragments (loop-invariant, B-operand of S^T = K Q^T)
  bf16x8 aq[2][2];
  for (int g = 0; g < 2; g++)
    for (int kk = 0; kk < 2; kk++)
      aq[g][kk] = __builtin_bit_cast(bf16x8, *reinterpret_cast<const short8*>(
          &Qg[(size_t)(q0 + g * 16 + m15) * 64 + kk * 32 + quad * 8]));

  // register frag buffers (single set each, consume-then-refill)
  short8 kf[8], vf[8];
#pragma unroll
  for (int mt = 0; mt < 4; mt++)
    for (int kk = 0; kk < 2; kk++) {
      kf[mt * 2 + kk] = KFRAG(ks, mt, kk);
      vf[mt * 2 + kk] = VFRAG(ks, mt, kk);
    }

  floatx4 o[2][4] = {};
  floatx4 lacc[2] = {};
  const short8 ones_s = {0x3f80, 0x3f80, 0x3f80, 0x3f80, 0x3f80, 0x3f80, 0x3f80, 0x3f80};
  const bf16x8 onesb = __builtin_bit_cast(bf16x8, ones_s);

  // ---- round 0: QK(t0) -> P(0) in strip[0]; refill kf <- K(t1) ----
  {
    unsigned short* sp = strips[wv][0];
    for (int g = 0; g < 2; g++) {
      floatx4 s[4] = {};
      for (int kk = 0; kk < 2; kk++)
#pragma unroll
        for (int mt = 0; mt < 4; mt++)
          s[mt] = __builtin_amdgcn_mfma_f32_16x16x32_bf16(
              __builtin_bit_cast(bf16x8, kf[mt * 2 + kk]), aq[g][kk], s[mt], 0, 0, 0);
#pragma unroll
      for (int mt = 0; mt < 4; mt++) {
        unsigned int d0 = ((unsigned int)f32_to_bf16_trunc(EXP2F(s[mt][1])) << 16) |
                          f32_to_bf16_trunc(EXP2F(s[mt][0]));
        unsigned int d1 = ((unsigned int)f32_to_bf16_trunc(EXP2F(s[mt][3])) << 16) |
                          f32_to_bf16_trunc(EXP2F(s[mt][2]));
        uint2 dd; dd.x = d0; dd.y = d1;
        *reinterpret_cast<uint2*>(&sp[(g * 16 + m15) * 72 + mt * 16 + quad * 4]) = dd;
      }
    }
#pragma unroll
    for (int mt = 0; mt < 4; mt++)
      for (int kk = 0; kk < 2; kk++) kf[mt * 2 + kk] = KFRAG(ks + 2, mt, kk);
    asm volatile("s_waitcnt lgkmcnt(0)" ::: "memory");
  }

  // ---- main loop r = 1..15: PV(t_{r-1}) + QK(t_r); no barriers ----
  for (int r = 1; r < 16; r++) {
    const int kt = 2 * r + ks;
    unsigned short* sp_prev = strips[wv][(r - 1) & 1];
    unsigned short* sp_cur = strips[wv][r & 1];

    // PV(t_{r-1}): strip + resident vf (= V(t_{r-1}))
    for (int kk2 = 0; kk2 < 2; kk2++)
      for (int g = 0; g < 2; g++) {
        bf16x8 a = *reinterpret_cast<const bf16x8*>(
            &sp_prev[(g * 16 + m15) * 72 + kk2 * 32 + quad * 8]);
        lacc[g] = __builtin_amdgcn_mfma_f32_16x16x32_bf16(a, onesb, lacc[g], 0, 0, 0);
#pragma unroll
        for (int nt = 0; nt < 4; nt++)
          o[g][nt] = __builtin_amdgcn_mfma_f32_16x16x32_bf16(
              a, __builtin_bit_cast(bf16x8, vf[nt * 2 + kk2]), o[g][nt], 0, 0, 0);
      }
    // refill vf <- V(t_r): consumed next round
#pragma unroll
    for (int nt = 0; nt < 4; nt++)
      for (int kk2 = 0; kk2 < 2; kk2++) vf[nt * 2 + kk2] = VFRAG(kt, nt, kk2);

    // QK(t_r) with resident kf, per q-half to limit register pressure
    for (int g = 0; g < 2; g++) {
      floatx4 s[4] = {};
      for (int kk = 0; kk < 2; kk++)
#pragma unroll
        for (int mt = 0; mt < 4; mt++)
          s[mt] = __builtin_amdgcn_mfma_f32_16x16x32_bf16(
              __builtin_bit_cast(bf16x8, kf[mt * 2 + kk]), aq[g][kk], s[mt], 0, 0, 0);
#pragma unroll
      for (int mt = 0; mt < 4; mt++) {
        unsigned int d0 = ((unsigned int)f32_to_bf16_trunc(EXP2F(s[mt][1])) << 16) |
                          f32_to_bf16_trunc(EXP2F(s[mt][0]));
        unsigned int d1 = ((unsigned int)f32_to_bf16_trunc(EXP2F(s[mt][3])) << 16) |
                          f32_to_bf16_trunc(EXP2F(s[mt][2]));
        uint2 dd; dd.x = d0; dd.y = d1;
        *reinterpret_cast<uint2*>(&sp_cur[(g * 16 + m15) * 72 + mt * 16 + quad * 4]) = dd;
      }
    }
    // refill kf <- K(t_{r+1})
    if (r < 15)
#pragma unroll
      for (int mt = 0; mt < 4; mt++)
        for (int kk = 0; kk < 2; kk++) kf[mt * 2 + kk] = KFRAG(kt + 2, mt, kk);
    asm volatile("s_waitcnt lgkmcnt(0)" ::: "memory");
  }

  // ---- epilogue: PV(t15) (strip[1], vf = V(t15)) ----
  for (int kk2 = 0; kk2 < 2; kk2++)
    for (int g = 0; g < 2; g++) {
      bf16x8 a = *reinterpret_cast<const bf16x8*>(
          &strips[wv][1][(g * 16 + m15) * 72 + kk2 * 32 + quad * 8]);
      lacc[g] = __builtin_amdgcn_mfma_f32_16x16x32_bf16(a, onesb, lacc[g], 0, 0, 0);
#pragma unroll
      for (int nt = 0; nt < 4; nt++)
        o[g][nt] = __builtin_amdgcn_mfma_f32_16x16x32_bf16(
            a, __builtin_bit_cast(bf16x8, vf[nt * 2 + kk2]), o[g][nt], 0, 0, 0);
    }
#undef KFRAG
#undef VFRAG

  // ---- cross-ks reduction (O and l are pure sums under no-max softmax) ----
  __syncthreads();  // all waves done with strips
  float* red = (float*)&strips[0][0][0];
  if (ks == 1) {
    floatx4* dst = (floatx4*)(red + (size_t)(qs * 64 + lane) * 40);
#pragma unroll
    for (int g = 0; g < 2; g++)
      for (int nt = 0; nt < 4; nt++) dst[g * 4 + nt] = o[g][nt];
    dst[8] = lacc[0];
    dst[9] = lacc[1];
  }
  __syncthreads();
  if (ks == 0) {
    const floatx4* src = (const floatx4*)(red + (size_t)(qs * 64 + lane) * 40);
#pragma unroll
    for (int g = 0; g < 2; g++)
      for (int nt = 0; nt < 4; nt++) o[g][nt] += src[g * 4 + nt];
    lacc[0] += src[8];
    lacc[1] += src[9];
    for (int g = 0; g < 2; g++)
      for (int r4 = 0; r4 < 4; r4++) {
        float rl = RCPF(lacc[g][r4]);
        int qq = q0 + g * 16 + quad * 4 + r4;
        for (int nt = 0; nt < 4; nt++)
          ctx[(size_t)(bb * T_DIM + qq) * E_DIM + h * 64 + nt * 16 + m15] =
              f32_to_bf16(o[g][nt][r4] * rl);
      }
  }
}

// ---- output projection: out = ctx @ Wo + bo (fp32) ----
__global__ __launch_bounds__(256) void gemm_out(const unsigned short* __restrict__ Actx,
                                                const unsigned short* __restrict__ Wt,
                                                const float* __restrict__ bias,
                                                float* __restrict__ out) {
  __shared__ unsigned short As[64 * 32];
  __shared__ unsigned short Bs[128 * 32];

  const int tid = threadIdx.x;
  const int lane = tid & 63, wv = tid >> 6;
  const int m15 = lane & 15, quad = lane >> 4;
  const int wm = (wv & 1) * 32, wn = (wv >> 1) * 64;
  const int m0 = blockIdx.x * 64, n0 = blockIdx.y * 128;

  floatx4 acc[2][4] = {};
  const int srow = lane >> 2, scol = (lane & 3) * 8;

  for (int k0 = 0; k0 < E_DIM; k0 += 32) {
    gload_lds16(&Actx[(size_t)(m0 + wv * 16 + srow) * E_DIM + k0 + scol], &As[wv * 512]);
    for (int cc = 0; cc < 2; cc++) {
      int c = wv * 2 + cc;
      gload_lds16(&Wt[(size_t)(n0 + c * 16 + srow) * E_DIM + k0 + scol], &Bs[c * 512]);
    }
    __syncthreads();
    bf16x8 af[2], bfr[4];
    for (int i = 0; i < 2; i++)
      af[i] = *reinterpret_cast<const bf16x8*>(&As[(wm + i * 16 + m15) * 32 + quad * 8]);
    for (int j = 0; j < 4; j++)
      bfr[j] = *reinterpret_cast<const bf16x8*>(&Bs[(wn + j * 16 + m15) * 32 + quad * 8]);
    for (int i = 0; i < 2; i++)
      for (int j = 0; j < 4; j++)
        acc[i][j] = __builtin_amdgcn_mfma_f32_16x16x32_bf16(af[i], bfr[j], acc[i][j], 0, 0, 0);
    __syncthreads();
  }

  for (int i = 0; i < 2; i++)
    for (int j = 0; j < 4; j++) {
      int gn = n0 + wn + j * 16 + m15;
      float bso = bias[gn];
      for (int r = 0; r < 4; r++) {
        int gm = m0 + wm + i * 16 + quad * 4 + r;
        out[(size_t)gm * E_DIM + gn] = acc[i][j][r] + bso;
      }
    }
}

extern "C" void kernel_launch(void* const* d_in, const int* in_sizes, int n_in,
                              void* d_out, int out_size, void* d_ws, size_t ws_size,
                              hipStream_t stream) {
  const float* query  = (const float*)d_in[0];
  const float* key_in = (const float*)d_in[1];
  const float* value  = (const float*)d_in[2];
  const float* Wq = (const float*)d_in[3];
  const float* bq = (const float*)d_in[4];
  const float* Wk = (const float*)d_in[5];
  const float* bk = (const float*)d_in[6];
  const float* Wv = (const float*)d_in[7];
  const float* bv = (const float*)d_in[8];
  const float* Wo = (const float*)d_in[9];
  const float* bo = (const float*)d_in[10];
  float* out = (float*)d_out;

  // ws layout (bf16): Wt[4][768][768] | Xb[3][4096][768] | QKV[3][4096][768] | VT[2][12][64][2048] | ctx[4096][768]
  unsigned short* ws  = (unsigned short*)d_ws;
  unsigned short* Wt  = ws;
  unsigned short* Xb  = Wt + (size_t)4 * E_DIM * E_DIM;
  unsigned short* QKV = Xb + (size_t)3 * M_TOT * E_DIM;
  unsigned short* VT  = QKV + (size_t)3 * M_TOT * E_DIM;
  unsigned short* ctx = VT + (size_t)N_B * N_H * H_D * T_DIM;

  dim3 tb(256);
  prep<<<dim3(11520), tb, 0, stream>>>(query, key_in, value, Wq, Wk, Wv, Wo, Xb, Wt);
  gemm_qkv<<<dim3(32, 6, 3), tb, 0, stream>>>(Xb, Wt, bq, bk, bv, QKV, VT);
  attn<<<dim3(32, 12, 2), tb, 0, stream>>>(QKV, VT, ctx);
  gemm_out<<<dim3(64, 6), tb, 0, stream>>>(ctx, Wt + (size_t)3 * E_DIM * E_DIM, bo, out);
  (void)in_sizes; (void)n_in; (void)out_size; (void)ws_size;
}

// Round 9
// 206.230 us; speedup vs baseline: 1.1667x; 1.1667x over previous
//
#include <hip/hip_runtime.h>
#include <math.h>

typedef __attribute__((ext_vector_type(4))) float  floatx4;
typedef __attribute__((ext_vector_type(8))) short  short8;
typedef __attribute__((ext_vector_type(4))) short  short4v;
typedef __attribute__((ext_vector_type(8))) __bf16 bf16x8;

#define E_DIM 768
#define T_DIM 2048
#define N_B   2
#define N_H   12
#define H_D   64
#define M_TOT 4096  /* N_B * T_DIM */

// 0.125 * log2(e): folded into Q so exp2() applies directly to QK^T output
#define Q_SCALE 0.1803368801111204f

#if __has_builtin(__builtin_amdgcn_exp2f)
#define EXP2F(x) __builtin_amdgcn_exp2f(x)
#else
#define EXP2F(x) exp2f(x)
#endif
#if __has_builtin(__builtin_amdgcn_rcpf)
#define RCPF(x) __builtin_amdgcn_rcpf(x)
#else
#define RCPF(x) (1.0f / (x))
#endif

__device__ __forceinline__ unsigned short f32_to_bf16(float f) {
  unsigned int u = __float_as_uint(f);
  u += 0x7fffu + ((u >> 16) & 1u);
  return (unsigned short)(u >> 16);
}

// truncating f32->bf16 (bias cancels in o/l since num+denom share P)
__device__ __forceinline__ unsigned short f32_to_bf16_trunc(float f) {
  return (unsigned short)(__float_as_uint(f) >> 16);
}

__device__ __forceinline__ void gload_lds16(const unsigned short* g, unsigned short* l) {
  __builtin_amdgcn_global_load_lds(
      (const __attribute__((address_space(1))) unsigned int*)(const void*)g,
      (__attribute__((address_space(3))) unsigned int*)(void*)l, 16, 0, 0);
}

// ---- prep: input bf16 convert (blocks 0..9215) + weight transpose (blocks 9216..11519) ----
__global__ __launch_bounds__(256) void prep(const float* __restrict__ q,
                                            const float* __restrict__ k,
                                            const float* __restrict__ v,
                                            const float* __restrict__ W0,
                                            const float* __restrict__ W1,
                                            const float* __restrict__ W2,
                                            const float* __restrict__ W3,
                                            unsigned short* __restrict__ Xb,
                                            unsigned short* __restrict__ Wt) {
  __shared__ float tile[32][33];
  const int bx = blockIdx.x;
  if (bx < 9216) {
    const int z = bx / 3072, inner = bx % 3072;
    const float* src = (z == 0) ? q : (z == 1) ? k : v;
    size_t idx = ((size_t)inner * 256 + threadIdx.x) * 4;
    float4 val = *reinterpret_cast<const float4*>(&src[idx]);
    short4v o;
    o[0] = (short)f32_to_bf16(val.x);
    o[1] = (short)f32_to_bf16(val.y);
    o[2] = (short)f32_to_bf16(val.z);
    o[3] = (short)f32_to_bf16(val.w);
    *reinterpret_cast<short4v*>(&Xb[(size_t)z * M_TOT * E_DIM + idx]) = o;
  } else {
    const int t = bx - 9216;
    const int z = t / 576, rem = t % 576;
    const float* W = (z == 0) ? W0 : (z == 1) ? W1 : (z == 2) ? W2 : W3;
    unsigned short* dst = Wt + (size_t)z * E_DIM * E_DIM;
    int k0 = (rem / 24) * 32, n0 = (rem % 24) * 32;
    int tx = threadIdx.x & 31, ty = threadIdx.x >> 5;
    for (int i = 0; i < 4; i++)
      tile[ty + i * 8][tx] = W[(size_t)(k0 + ty + i * 8) * E_DIM + n0 + tx];
    __syncthreads();
    for (int i = 0; i < 4; i++)
      dst[(size_t)(n0 + ty + i * 8) * E_DIM + k0 + tx] = f32_to_bf16(tile[tx][ty + i * 8]);
  }
}

// ---- QKV projection: BK=64, XOR-swizzled chunk staging.
// z=2 (V) writes transposed VT[b][h][d][t] directly.
__global__ __launch_bounds__(256) void gemm_qkv(const unsigned short* __restrict__ Xb,
                                                const unsigned short* __restrict__ WtAll,
                                                const float* __restrict__ bq,
                                                const float* __restrict__ bk,
                                                const float* __restrict__ bv,
                                                unsigned short* __restrict__ outQKV,
                                                unsigned short* __restrict__ VTout) {
  __shared__ unsigned short As[128 * 64];  // [row][col], chunk (row,dc) holds global dc^(row&7)
  __shared__ unsigned short Bs[128 * 64];

  const int z = blockIdx.z;
  const unsigned short* A = Xb + (size_t)z * M_TOT * E_DIM;
  const float* bias = (z == 0) ? bq : (z == 1) ? bk : bv;
  const unsigned short* W = WtAll + (size_t)z * E_DIM * E_DIM;
  unsigned short* out = outQKV + (size_t)z * M_TOT * E_DIM;
  const float scale = (z == 0) ? Q_SCALE : 1.0f;

  const int tid = threadIdx.x;
  const int lane = tid & 63, wv = tid >> 6;
  const int m15 = lane & 15, quad = lane >> 4;
  const int wm = (wv & 1) * 64, wn = (wv >> 1) * 64;
  const int m0 = blockIdx.x * 128, n0 = blockIdx.y * 128;

  floatx4 acc[4][4] = {};
  const int sw = m15 & 7;  // read-side chunk swizzle key

  for (int k0 = 0; k0 < E_DIM; k0 += 64) {
#pragma unroll
    for (int i = 0; i < 4; i++) {
      int c = tid + i * 256;           // chunk id 0..1023
      int row = c >> 3, dc = c & 7;
      int dcs = dc ^ (row & 7);
      gload_lds16(&A[(size_t)(m0 + row) * E_DIM + k0 + dcs * 8], &As[c * 8]);
      gload_lds16(&W[(size_t)(n0 + row) * E_DIM + k0 + dcs * 8], &Bs[c * 8]);
    }
    __syncthreads();
#pragma unroll
    for (int kk = 0; kk < 2; kk++) {
      bf16x8 af[4], bfr[4];
      for (int i = 0; i < 4; i++)
        af[i] = *reinterpret_cast<const bf16x8*>(
            &As[(wm + i * 16 + m15) * 64 + (((kk * 4 + quad) ^ sw) * 8)]);
      for (int j = 0; j < 4; j++)
        bfr[j] = *reinterpret_cast<const bf16x8*>(
            &Bs[(wn + j * 16 + m15) * 64 + (((kk * 4 + quad) ^ sw) * 8)]);
      for (int i = 0; i < 4; i++)
        for (int j = 0; j < 4; j++)
          acc[i][j] = __builtin_amdgcn_mfma_f32_16x16x32_bf16(af[i], bfr[j], acc[i][j], 0, 0, 0);
    }
    __syncthreads();
  }

  if (z == 2) {
    for (int i = 0; i < 4; i++)
      for (int j = 0; j < 4; j++) {
        int gn = n0 + wn + j * 16 + m15;
        int hh = gn >> 6, d = gn & 63;
        float bso = bias[gn];
        int gm0 = m0 + wm + i * 16 + quad * 4;
        int bb2 = gm0 >> 11, t0 = gm0 & 2047;
        unsigned int d0 = ((unsigned int)f32_to_bf16(acc[i][j][1] + bso) << 16) |
                          f32_to_bf16(acc[i][j][0] + bso);
        unsigned int d1 = ((unsigned int)f32_to_bf16(acc[i][j][3] + bso) << 16) |
                          f32_to_bf16(acc[i][j][2] + bso);
        uint2 dd; dd.x = d0; dd.y = d1;
        *reinterpret_cast<uint2*>(
            &VTout[(((size_t)bb2 * N_H + hh) * H_D + d) * T_DIM + t0]) = dd;
      }
  } else {
    for (int i = 0; i < 4; i++)
      for (int j = 0; j < 4; j++) {
        int gn = n0 + wn + j * 16 + m15;
        int h = gn >> 6, d = gn & 63;
        float bso = bias[gn];
        for (int r = 0; r < 4; r++) {
          int gm = m0 + wm + i * 16 + quad * 4 + r;
          int bb = gm >> 11, tt = gm & 2047;
          float vv = (acc[i][j][r] + bso) * scale;
          out[(((size_t)bb * N_H + h) * T_DIM + tt) * H_D + d] = f32_to_bf16(vv);
        }
      }
  }
}

// ---- flash attention: PV-FIRST lagged rounds. 256 thr, qs x ks wave split.
// Round r: PV(t_{r-1}) from strip+resident vf (no deps at round top), vf refill,
// QK(t_r) from LDS K (global_load_lds dbuf, one-round slack), exp -> strip.
// Single wave-private strip (PV reads precede P writes, DS in-order).
// No-max softmax; l via ones-MFMA; cross-ks reduction through LDS at the end.
__global__ __launch_bounds__(256, 3) void attn(const unsigned short* __restrict__ QKV,
                                               const unsigned short* __restrict__ VT,
                                               unsigned short* __restrict__ ctx) {
  __shared__ unsigned short Kbuf[2][2][64 * 64];  // [ping][parity][key][d-swz] 32 KB
  __shared__ unsigned short strips[4][32 * 72];   // per-wave P strip 18.4 KB

  const int qb = blockIdx.x, h = blockIdx.y, bb = blockIdx.z;
  const size_t headoff = (((size_t)bb * N_H + h) * T_DIM) * H_D;
  const unsigned short* Qg = QKV + headoff;
  const unsigned short* Kg = QKV + (size_t)M_TOT * E_DIM + headoff;
  const unsigned short* VTg = VT + (((size_t)bb * N_H + h) * H_D) * T_DIM;

  const int tid = threadIdx.x, lane = tid & 63, wv = tid >> 6;
  const int m15 = lane & 15, quad = lane >> 4;
  const int qs = wv & 1, ks = wv >> 1;
  const int q0 = qb * 64 + qs * 32;

  // stage tiles {t0, t0+1} into Kbuf[ping]; d-chunks permuted by key for
  // conflict-floor swizzled frag reads (R7-verified pattern).
  auto stage = [&](int t0, int ping) {
#pragma unroll
    for (int i = 0; i < 4; i++) {
      int c = tid + i * 256;
      int par = c >> 9, cc = c & 511;
      int key = cc >> 3, dc = cc & 7;
      int dcs = dc ^ (key & 7);
      gload_lds16(&Kg[((size_t)(t0 + par) * 64 + key) * 64 + dcs * 8],
                  &Kbuf[ping][par][cc * 8]);
    }
  };

  const unsigned short* vbase = VTg + (size_t)(m15 * 2048 + quad * 8);
#define VFRAG(kt, nt, kk2) \
  (*reinterpret_cast<const short8*>(vbase + (size_t)(nt) * 32768 + (kt) * 64 + (kk2) * 32))

  stage(0, 0);

  // Q fragments (loop-invariant, B-operand of S^T = K Q^T)
  bf16x8 aq[2][2];
  for (int g = 0; g < 2; g++)
    for (int kk = 0; kk < 2; kk++)
      aq[g][kk] = __builtin_bit_cast(bf16x8, *reinterpret_cast<const short8*>(
          &Qg[(size_t)(q0 + g * 16 + m15) * 64 + kk * 32 + quad * 8]));

  // vf holds V(t_{r-1}) at the top of round r; prologue: V(t_0)
  short8 vf[8];
#pragma unroll
  for (int nt = 0; nt < 4; nt++)
    for (int kk2 = 0; kk2 < 2; kk2++) vf[nt * 2 + kk2] = VFRAG(ks, nt, kk2);

  floatx4 o[2][4] = {};
  floatx4 lacc[2] = {};
  const short8 ones_s = {0x3f80, 0x3f80, 0x3f80, 0x3f80, 0x3f80, 0x3f80, 0x3f80, 0x3f80};
  const bf16x8 onesb = __builtin_bit_cast(bf16x8, ones_s);
  unsigned short* strip = strips[wv];

  for (int r = 0; r < 16; r++) {
    __syncthreads();  // staging(round r) + vf loads visible (both one round old)
    if (r < 15) stage(2 * (r + 1), (r + 1) & 1);
    const int kt = 2 * r + ks;
    const unsigned short* Kt = Kbuf[r & 1][ks];

    if (r > 0) {
      // PV(t_{r-1}): strip + resident vf -- no dependencies, fills MFMA pipe now
      for (int kk2 = 0; kk2 < 2; kk2++)
        for (int g = 0; g < 2; g++) {
          bf16x8 a = *reinterpret_cast<const bf16x8*>(
              &strip[(g * 16 + m15) * 72 + kk2 * 32 + quad * 8]);
          lacc[g] = __builtin_amdgcn_mfma_f32_16x16x32_bf16(a, onesb, lacc[g], 0, 0, 0);
#pragma unroll
          for (int nt = 0; nt < 4; nt++)
            o[g][nt] = __builtin_amdgcn_mfma_f32_16x16x32_bf16(
                a, __builtin_bit_cast(bf16x8, vf[nt * 2 + kk2]), o[g][nt], 0, 0, 0);
        }
      // refill vf <- V(t_r), consumed next round (full round of slack)
#pragma unroll
      for (int nt = 0; nt < 4; nt++)
        for (int kk2 = 0; kk2 < 2; kk2++) vf[nt * 2 + kk2] = VFRAG(kt, nt, kk2);
    }

    // QK(t_r): S^T[key][q] = K Q^T; exp -> strip (writes after this round's reads)
    for (int g = 0; g < 2; g++) {
      floatx4 s[4] = {};
      for (int kk = 0; kk < 2; kk++)
#pragma unroll
        for (int mt = 0; mt < 4; mt++) {
          bf16x8 a = *reinterpret_cast<const bf16x8*>(
              &Kt[(mt * 16 + m15) * 64 + (((kk * 4 + quad) ^ (m15 & 7)) * 8)]);
          s[mt] = __builtin_amdgcn_mfma_f32_16x16x32_bf16(a, aq[g][kk], s[mt], 0, 0, 0);
        }
#pragma unroll
      for (int mt = 0; mt < 4; mt++) {
        unsigned int d0 = ((unsigned int)f32_to_bf16_trunc(EXP2F(s[mt][1])) << 16) |
                          f32_to_bf16_trunc(EXP2F(s[mt][0]));
        unsigned int d1 = ((unsigned int)f32_to_bf16_trunc(EXP2F(s[mt][3])) << 16) |
                          f32_to_bf16_trunc(EXP2F(s[mt][2]));
        uint2 dd; dd.x = d0; dd.y = d1;
        *reinterpret_cast<uint2*>(&strip[(g * 16 + m15) * 72 + mt * 16 + quad * 4]) = dd;
      }
    }
  }

  // ---- epilogue: PV(t_15); vf = V(t_15) refilled at r=15 ----
  for (int kk2 = 0; kk2 < 2; kk2++)
    for (int g = 0; g < 2; g++) {
      bf16x8 a = *reinterpret_cast<const bf16x8*>(
          &strip[(g * 16 + m15) * 72 + kk2 * 32 + quad * 8]);
      lacc[g] = __builtin_amdgcn_mfma_f32_16x16x32_bf16(a, onesb, lacc[g], 0, 0, 0);
#pragma unroll
      for (int nt = 0; nt < 4; nt++)
        o[g][nt] = __builtin_amdgcn_mfma_f32_16x16x32_bf16(
            a, __builtin_bit_cast(bf16x8, vf[nt * 2 + kk2]), o[g][nt], 0, 0, 0);
    }
#undef VFRAG

  // ---- cross-ks reduction (O and l are pure sums under no-max softmax) ----
  __syncthreads();  // all waves done with Kbuf/strips
  float* red = (float*)&Kbuf[0][0][0];
  if (ks == 1) {
    floatx4* dst = (floatx4*)(red + (size_t)(qs * 64 + lane) * 40);
#pragma unroll
    for (int g = 0; g < 2; g++)
      for (int nt = 0; nt < 4; nt++) dst[g * 4 + nt] = o[g][nt];
    dst[8] = lacc[0];
    dst[9] = lacc[1];
  }
  __syncthreads();
  if (ks == 0) {
    const floatx4* src = (const floatx4*)(red + (size_t)(qs * 64 + lane) * 40);
#pragma unroll
    for (int g = 0; g < 2; g++)
      for (int nt = 0; nt < 4; nt++) o[g][nt] += src[g * 4 + nt];
    lacc[0] += src[8];
    lacc[1] += src[9];
    for (int g = 0; g < 2; g++)
      for (int r4 = 0; r4 < 4; r4++) {
        float rl = RCPF(lacc[g][r4]);
        int qq = q0 + g * 16 + quad * 4 + r4;
        for (int nt = 0; nt < 4; nt++)
          ctx[(size_t)(bb * T_DIM + qq) * E_DIM + h * 64 + nt * 16 + m15] =
              f32_to_bf16(o[g][nt][r4] * rl);
      }
  }
}

// ---- output projection: out = ctx @ Wo + bo (fp32) ----
__global__ __launch_bounds__(256) void gemm_out(const unsigned short* __restrict__ Actx,
                                                const unsigned short* __restrict__ Wt,
                                                const float* __restrict__ bias,
                                                float* __restrict__ out) {
  __shared__ unsigned short As[64 * 32];
  __shared__ unsigned short Bs[128 * 32];

  const int tid = threadIdx.x;
  const int lane = tid & 63, wv = tid >> 6;
  const int m15 = lane & 15, quad = lane >> 4;
  const int wm = (wv & 1) * 32, wn = (wv >> 1) * 64;
  const int m0 = blockIdx.x * 64, n0 = blockIdx.y * 128;

  floatx4 acc[2][4] = {};
  const int srow = lane >> 2, scol = (lane & 3) * 8;

  for (int k0 = 0; k0 < E_DIM; k0 += 32) {
    gload_lds16(&Actx[(size_t)(m0 + wv * 16 + srow) * E_DIM + k0 + scol], &As[wv * 512]);
    for (int cc = 0; cc < 2; cc++) {
      int c = wv * 2 + cc;
      gload_lds16(&Wt[(size_t)(n0 + c * 16 + srow) * E_DIM + k0 + scol], &Bs[c * 512]);
    }
    __syncthreads();
    bf16x8 af[2], bfr[4];
    for (int i = 0; i < 2; i++)
      af[i] = *reinterpret_cast<const bf16x8*>(&As[(wm + i * 16 + m15) * 32 + quad * 8]);
    for (int j = 0; j < 4; j++)
      bfr[j] = *reinterpret_cast<const bf16x8*>(&Bs[(wn + j * 16 + m15) * 32 + quad * 8]);
    for (int i = 0; i < 2; i++)
      for (int j = 0; j < 4; j++)
        acc[i][j] = __builtin_amdgcn_mfma_f32_16x16x32_bf16(af[i], bfr[j], acc[i][j], 0, 0, 0);
    __syncthreads();
  }

  for (int i = 0; i < 2; i++)
    for (int j = 0; j < 4; j++) {
      int gn = n0 + wn + j * 16 + m15;
      float bso = bias[gn];
      for (int r = 0; r < 4; r++) {
        int gm = m0 + wm + i * 16 + quad * 4 + r;
        out[(size_t)gm * E_DIM + gn] = acc[i][j][r] + bso;
      }
    }
}

extern "C" void kernel_launch(void* const* d_in, const int* in_sizes, int n_in,
                              void* d_out, int out_size, void* d_ws, size_t ws_size,
                              hipStream_t stream) {
  const float* query  = (const float*)d_in[0];
  const float* key_in = (const float*)d_in[1];
  const float* value  = (const float*)d_in[2];
  const float* Wq = (const float*)d_in[3];
  const float* bq = (const float*)d_in[4];
  const float* Wk = (const float*)d_in[5];
  const float* bk = (const float*)d_in[6];
  const float* Wv = (const float*)d_in[7];
  const float* bv = (const float*)d_in[8];
  const float* Wo = (const float*)d_in[9];
  const float* bo = (const float*)d_in[10];
  float* out = (float*)d_out;

  // ws layout (bf16): Wt[4][768][768] | Xb[3][4096][768] | QKV[3][4096][768] | VT[2][12][64][2048] | ctx[4096][768]
  unsigned short* ws  = (unsigned short*)d_ws;
  unsigned short* Wt  = ws;
  unsigned short* Xb  = Wt + (size_t)4 * E_DIM * E_DIM;
  unsigned short* QKV = Xb + (size_t)3 * M_TOT * E_DIM;
  unsigned short* VT  = QKV + (size_t)3 * M_TOT * E_DIM;
  unsigned short* ctx = VT + (size_t)N_B * N_H * H_D * T_DIM;

  dim3 tb(256);
  prep<<<dim3(11520), tb, 0, stream>>>(query, key_in, value, Wq, Wk, Wv, Wo, Xb, Wt);
  gemm_qkv<<<dim3(32, 6, 3), tb, 0, stream>>>(Xb, Wt, bq, bk, bv, QKV, VT);
  attn<<<dim3(32, 12, 2), tb, 0, stream>>>(QKV, VT, ctx);
  gemm_out<<<dim3(64, 6), tb, 0, stream>>>(ctx, Wt + (size_t)3 * E_DIM * E_DIM, bo, out);
  (void)in_sizes; (void)n_in; (void)out_size; (void)ws_size;
}